// Round 1
// baseline (1490.515 us; speedup 1.0000x reference)
//
#include <hip/hip_runtime.h>

// GCN 2-layer inference, fp32 baseline.
// Layout of d_ws (floats):
//   [0 .. N)                      deg -> dis (in place)
//   [DIS_PAD .. DIS_PAD+N*128)    h  (layer-1 GEMM out); later aliased by g (N*64)
//   [DIS_PAD+N*128 .. +2*N*128)   out1 (layer-1 aggregated, pre-relu)
static constexpr int DIS_PAD = 131072;  // floats; 512 KB, >= N

__device__ __forceinline__ void atomic_add_f32(float* p, float v) {
  __hip_atomic_fetch_add(p, v, __ATOMIC_RELAXED, __HIP_MEMORY_SCOPE_AGENT);
}

__global__ __launch_bounds__(256) void deg_kernel(const int* __restrict__ dst,
                                                  float* __restrict__ deg, int nE) {
  int i = blockIdx.x * 256 + threadIdx.x;
  if (i < nE) atomic_add_f32(&deg[dst[i]], 1.0f);
}

__global__ __launch_bounds__(256) void dis_kernel(float* __restrict__ degdis, int n) {
  int i = blockIdx.x * 256 + threadIdx.x;
  if (i < n) degdis[i] = rsqrtf(degdis[i] + 1.0f);  // +1 = self loop
}

// H[n, COLS] = (RELU_IN ? relu(X) : X)[n,128] @ W[128, COLS]
template <int COLS, bool RELU_IN>
__global__ __launch_bounds__(256) void gemm_kernel(const float* __restrict__ X,
                                                   const float* __restrict__ W,
                                                   float* __restrict__ H, int n) {
  __shared__ float sW[128 * COLS];  // 64 KB (COLS=128) / 32 KB (COLS=64)
  for (int i = threadIdx.x; i < 128 * COLS; i += 256) sW[i] = W[i];
  __syncthreads();
  const int wave = threadIdx.x >> 6;
  const int lane = threadIdx.x & 63;
  constexpr int CPL = COLS / 64;  // cols per lane
  int row0 = blockIdx.x * 64 + wave * 16;
  int rend = row0 + 16;
  if (rend > n) rend = n;
  for (int r = row0; r < rend; ++r) {
    float acc[CPL];
#pragma unroll
    for (int c = 0; c < CPL; ++c) acc[c] = 0.f;
    const float4* xrow = reinterpret_cast<const float4*>(X + (size_t)r * 128);
#pragma unroll 4
    for (int k4 = 0; k4 < 32; ++k4) {
      float4 xv = xrow[k4];
      if (RELU_IN) {
        xv.x = fmaxf(xv.x, 0.f); xv.y = fmaxf(xv.y, 0.f);
        xv.z = fmaxf(xv.z, 0.f); xv.w = fmaxf(xv.w, 0.f);
      }
#pragma unroll
      for (int c = 0; c < CPL; ++c) {
        const int col = lane + 64 * c;
        acc[c] = fmaf(xv.x, sW[(4 * k4 + 0) * COLS + col], acc[c]);
        acc[c] = fmaf(xv.y, sW[(4 * k4 + 1) * COLS + col], acc[c]);
        acc[c] = fmaf(xv.z, sW[(4 * k4 + 2) * COLS + col], acc[c]);
        acc[c] = fmaf(xv.w, sW[(4 * k4 + 3) * COLS + col], acc[c]);
      }
    }
#pragma unroll
    for (int c = 0; c < CPL; ++c) H[(size_t)r * COLS + lane + 64 * c] = acc[c];
  }
}

// out[i,c] = bias[c] + dis[i]^2 * h[i,c]   (self-loop term + bias)
template <int COLS>
__global__ __launch_bounds__(256) void init_out_kernel(const float* __restrict__ h,
                                                       const float* __restrict__ dis,
                                                       const float* __restrict__ bias,
                                                       float* __restrict__ out, int n) {
  int i = blockIdx.x * 256 + threadIdx.x;
  if (i < n * COLS) {
    int node = i / COLS;
    int c = i & (COLS - 1);
    float ds = dis[node];
    out[i] = bias[c] + ds * ds * h[i];
  }
}

// out[dst] += dis[src]*dis[dst] * h[src], one wave per edge (grid-stride)
template <int COLS>
__global__ __launch_bounds__(256) void edge_agg_kernel(const int* __restrict__ src,
                                                       const int* __restrict__ dst,
                                                       const float* __restrict__ dis,
                                                       const float* __restrict__ h,
                                                       float* __restrict__ out, int nE) {
  const int lane = threadIdx.x & 63;
  const int wv = blockIdx.x * 4 + (threadIdx.x >> 6);
  const int nwv = gridDim.x * 4;
  constexpr int CPL = COLS / 64;
  for (int e = wv; e < nE; e += nwv) {
    const int s = src[e], d = dst[e];
    const float w = dis[s] * dis[d];
    const float* hrow = h + (size_t)s * COLS;
    float* orow = out + (size_t)d * COLS;
#pragma unroll
    for (int c = 0; c < CPL; ++c) {
      atomic_add_f32(&orow[lane + 64 * c], w * hrow[lane + 64 * c]);
    }
  }
}

extern "C" void kernel_launch(void* const* d_in, const int* in_sizes, int n_in,
                              void* d_out, int out_size, void* d_ws, size_t ws_size,
                              hipStream_t stream) {
  const float* x  = (const float*)d_in[0];
  const int* ei   = (const int*)d_in[1];   // [2, E] int32 (JAX x64 off)
  const float* W1 = (const float*)d_in[2];
  const float* b1 = (const float*)d_in[3];
  const float* W2 = (const float*)d_in[4];
  const float* b2 = (const float*)d_in[5];
  float* out = (float*)d_out;

  const int N = in_sizes[0] / 128;  // 100000
  const int E = in_sizes[1] / 2;    // 1600000
  const int* srcI = ei;
  const int* dstI = ei + E;

  float* dis  = (float*)d_ws;
  float* h    = dis + DIS_PAD;              // N*128 floats
  float* out1 = h + (size_t)N * 128;        // N*128 floats
  float* g    = h;                          // layer-2 GEMM out aliases dead h (N*64)

  // 1. degree -> dis
  hipMemsetAsync(dis, 0, (size_t)N * sizeof(float), stream);
  deg_kernel<<<(E + 255) / 256, 256, 0, stream>>>(dstI, dis, E);
  dis_kernel<<<(N + 255) / 256, 256, 0, stream>>>(dis, N);

  // 2. layer 1
  gemm_kernel<128, false><<<(N + 63) / 64, 256, 0, stream>>>(x, W1, h, N);
  init_out_kernel<128><<<((size_t)N * 128 + 255) / 256, 256, 0, stream>>>(h, dis, b1, out1, N);
  edge_agg_kernel<128><<<4096, 256, 0, stream>>>(srcI, dstI, dis, h, out1, E);

  // 3. layer 2 (relu fused into GEMM2 load)
  gemm_kernel<64, true><<<(N + 63) / 64, 256, 0, stream>>>(out1, W2, g, N);
  init_out_kernel<64><<<((size_t)N * 64 + 255) / 256, 256, 0, stream>>>(g, dis, b2, out, N);
  edge_agg_kernel<64><<<4096, 256, 0, stream>>>(srcI, dstI, dis, g, out, E);
}

// Round 2
// 829.445 us; speedup vs baseline: 1.7970x; 1.7970x over previous
//
#include <hip/hip_runtime.h>

// GCN 2-layer inference via CSR gather (no fp32 atomics).
// ws layout (all regions 512KB/16B aligned):
//   dis       NPAD floats
//   degi      NPAD ints
//   row_start NPAD ints (N+1 used)
//   cursor    NPAD ints
//   bsum      4096 ints
//   csr_src   E ints
//   h         N*128 floats  (layer-1 GEMM out; layer-2 GEMM out aliases it)
//   out1      N*128 floats
static constexpr int NPAD = 131072;

__global__ __launch_bounds__(256) void deg_kernel(const int* __restrict__ dst,
                                                  int* __restrict__ degi, int nE) {
  int i = blockIdx.x * 256 + threadIdx.x;
  if (i < nE) atomicAdd(&degi[dst[i]], 1);
}

__global__ __launch_bounds__(256) void dis_kernel(const int* __restrict__ degi,
                                                  float* __restrict__ dis, int n) {
  int i = blockIdx.x * 256 + threadIdx.x;
  if (i < n) dis[i] = rsqrtf((float)degi[i] + 1.0f);  // +1 = self loop
}

__global__ __launch_bounds__(256) void block_sum_kernel(const int* __restrict__ degi,
                                                        int* __restrict__ bsum, int n) {
  __shared__ int sm[256];
  int i = blockIdx.x * 256 + threadIdx.x;
  sm[threadIdx.x] = (i < n) ? degi[i] : 0;
  __syncthreads();
  for (int s = 128; s > 0; s >>= 1) {
    if (threadIdx.x < s) sm[threadIdx.x] += sm[threadIdx.x + s];
    __syncthreads();
  }
  if (threadIdx.x == 0) bsum[blockIdx.x] = sm[0];
}

__global__ __launch_bounds__(512) void scan_bsum_kernel(int* __restrict__ bsum, int nb) {
  __shared__ int sm[512];
  int v = (threadIdx.x < nb) ? bsum[threadIdx.x] : 0;
  sm[threadIdx.x] = v;
  __syncthreads();
  for (int off = 1; off < 512; off <<= 1) {
    int t = (threadIdx.x >= off) ? sm[threadIdx.x - off] : 0;
    __syncthreads();
    sm[threadIdx.x] += t;
    __syncthreads();
  }
  if (threadIdx.x < nb) bsum[threadIdx.x] = sm[threadIdx.x] - v;  // exclusive
}

__global__ __launch_bounds__(256) void scan_local_kernel(const int* __restrict__ degi,
                                                         const int* __restrict__ bsum,
                                                         int* __restrict__ row_start,
                                                         int* __restrict__ cursor, int n) {
  __shared__ int sm[256];
  int i = blockIdx.x * 256 + threadIdx.x;
  int v = (i < n) ? degi[i] : 0;
  sm[threadIdx.x] = v;
  __syncthreads();
  for (int off = 1; off < 256; off <<= 1) {
    int t = (threadIdx.x >= off) ? sm[threadIdx.x - off] : 0;
    __syncthreads();
    sm[threadIdx.x] += t;
    __syncthreads();
  }
  int excl = sm[threadIdx.x] - v + bsum[blockIdx.x];
  if (i < n) { row_start[i] = excl; cursor[i] = excl; }
  if (i == n - 1) row_start[n] = excl + v;  // = E
}

__global__ __launch_bounds__(256) void fill_csr_kernel(const int* __restrict__ src,
                                                       const int* __restrict__ dst,
                                                       int* __restrict__ cursor,
                                                       int* __restrict__ csr, int nE) {
  int i = blockIdx.x * 256 + threadIdx.x;
  if (i < nE) {
    int pos = atomicAdd(&cursor[dst[i]], 1);
    csr[pos] = src[i];
  }
}

// H[n, COLS] = (RELU_IN ? relu(X) : X)[n,128] @ W[128, COLS]
template <int COLS, bool RELU_IN>
__global__ __launch_bounds__(256) void gemm_kernel(const float* __restrict__ X,
                                                   const float* __restrict__ W,
                                                   float* __restrict__ H, int n) {
  __shared__ float sW[128 * COLS];
  for (int i = threadIdx.x; i < 128 * COLS; i += 256) sW[i] = W[i];
  __syncthreads();
  const int wave = threadIdx.x >> 6;
  const int lane = threadIdx.x & 63;
  constexpr int CPL = COLS / 64;
  int row0 = blockIdx.x * 64 + wave * 16;
  int rend = row0 + 16;
  if (rend > n) rend = n;
  for (int r = row0; r < rend; ++r) {
    float acc[CPL];
#pragma unroll
    for (int c = 0; c < CPL; ++c) acc[c] = 0.f;
    const float4* xrow = reinterpret_cast<const float4*>(X + (size_t)r * 128);
#pragma unroll 4
    for (int k4 = 0; k4 < 32; ++k4) {
      float4 xv = xrow[k4];
      if (RELU_IN) {
        xv.x = fmaxf(xv.x, 0.f); xv.y = fmaxf(xv.y, 0.f);
        xv.z = fmaxf(xv.z, 0.f); xv.w = fmaxf(xv.w, 0.f);
      }
#pragma unroll
      for (int c = 0; c < CPL; ++c) {
        const int col = lane + 64 * c;
        acc[c] = fmaf(xv.x, sW[(4 * k4 + 0) * COLS + col], acc[c]);
        acc[c] = fmaf(xv.y, sW[(4 * k4 + 1) * COLS + col], acc[c]);
        acc[c] = fmaf(xv.z, sW[(4 * k4 + 2) * COLS + col], acc[c]);
        acc[c] = fmaf(xv.w, sW[(4 * k4 + 3) * COLS + col], acc[c]);
      }
    }
#pragma unroll
    for (int c = 0; c < CPL; ++c) H[(size_t)r * COLS + lane + 64 * c] = acc[c];
  }
}

// One wave per dst node: out[d] = dis[d]*(sum_{s in N(d)} dis[s]*h[s] + dis[d]*h[d]) + b
template <int COLS>
__global__ __launch_bounds__(256) void agg_kernel(const int* __restrict__ row_start,
                                                  const int* __restrict__ csr,
                                                  const float* __restrict__ dis,
                                                  const float* __restrict__ h,
                                                  const float* __restrict__ bias,
                                                  float* __restrict__ out, int n) {
  const int lane = threadIdx.x & 63;
  int wv = blockIdx.x * 4 + (threadIdx.x >> 6);
  const int nwv = gridDim.x * 4;
  for (int d = wv; d < n; d += nwv) {
    const int e0 = row_start[d], e1 = row_start[d + 1];
    const float dd = dis[d];
    if (COLS == 128) {
      float2 hv = ((const float2*)(h + (size_t)d * 128))[lane];
      float acx = dd * hv.x, acy = dd * hv.y;
      int e = e0;
      for (; e + 1 < e1; e += 2) {
        int sa = csr[e], sb = csr[e + 1];
        float wa = dis[sa], wb = dis[sb];
        float2 ha = ((const float2*)(h + (size_t)sa * 128))[lane];
        float2 hb = ((const float2*)(h + (size_t)sb * 128))[lane];
        acx = fmaf(wa, ha.x, acx); acy = fmaf(wa, ha.y, acy);
        acx = fmaf(wb, hb.x, acx); acy = fmaf(wb, hb.y, acy);
      }
      if (e < e1) {
        int sa = csr[e];
        float wa = dis[sa];
        float2 ha = ((const float2*)(h + (size_t)sa * 128))[lane];
        acx = fmaf(wa, ha.x, acx); acy = fmaf(wa, ha.y, acy);
      }
      float2 bv = ((const float2*)bias)[lane];
      float2 o;
      o.x = fmaf(dd, acx, bv.x);
      o.y = fmaf(dd, acy, bv.y);
      ((float2*)(out + (size_t)d * 128))[lane] = o;
    } else {
      float acc = dd * h[(size_t)d * 64 + lane];
      int e = e0;
      for (; e + 1 < e1; e += 2) {
        int sa = csr[e], sb = csr[e + 1];
        float wa = dis[sa], wb = dis[sb];
        float ha = h[(size_t)sa * 64 + lane];
        float hb = h[(size_t)sb * 64 + lane];
        acc = fmaf(wa, ha, acc);
        acc = fmaf(wb, hb, acc);
      }
      if (e < e1) {
        int sa = csr[e];
        acc = fmaf(dis[sa], h[(size_t)sa * 64 + lane], acc);
      }
      out[(size_t)d * 64 + lane] = fmaf(dd, acc, bias[lane]);
    }
  }
}

extern "C" void kernel_launch(void* const* d_in, const int* in_sizes, int n_in,
                              void* d_out, int out_size, void* d_ws, size_t ws_size,
                              hipStream_t stream) {
  const float* x  = (const float*)d_in[0];
  const int* ei   = (const int*)d_in[1];   // [2, E] int32
  const float* W1 = (const float*)d_in[2];
  const float* b1 = (const float*)d_in[3];
  const float* W2 = (const float*)d_in[4];
  const float* b2 = (const float*)d_in[5];
  float* out = (float*)d_out;

  const int N = in_sizes[0] / 128;  // 100000
  const int E = in_sizes[1] / 2;    // 1600000
  const int* srcI = ei;
  const int* dstI = ei + E;

  char* w = (char*)d_ws;
  float* dis      = (float*)w;                 w += (size_t)NPAD * 4;
  int* degi       = (int*)w;                   w += (size_t)NPAD * 4;
  int* row_start  = (int*)w;                   w += (size_t)NPAD * 4;
  int* cursor     = (int*)w;                   w += (size_t)NPAD * 4;
  int* bsum       = (int*)w;                   w += 4096 * 4;
  int* csr_src    = (int*)w;                   w += (size_t)E * 4;
  float* h        = (float*)w;                 w += (size_t)N * 128 * 4;
  float* out1     = (float*)w;
  float* g        = h;  // layer-2 GEMM out aliases dead h

  const int nb = (N + 255) / 256;  // 391 <= 512

  // CSR build
  hipMemsetAsync(degi, 0, (size_t)N * sizeof(int), stream);
  deg_kernel<<<(E + 255) / 256, 256, 0, stream>>>(dstI, degi, E);
  dis_kernel<<<(N + 255) / 256, 256, 0, stream>>>(degi, dis, N);
  block_sum_kernel<<<nb, 256, 0, stream>>>(degi, bsum, N);
  scan_bsum_kernel<<<1, 512, 0, stream>>>(bsum, nb);
  scan_local_kernel<<<nb, 256, 0, stream>>>(degi, bsum, row_start, cursor, N);
  fill_csr_kernel<<<(E + 255) / 256, 256, 0, stream>>>(srcI, dstI, cursor, csr_src, E);

  // layer 1
  gemm_kernel<128, false><<<(N + 63) / 64, 256, 0, stream>>>(x, W1, h, N);
  agg_kernel<128><<<2048, 256, 0, stream>>>(row_start, csr_src, dis, h, b1, out1, N);

  // layer 2 (relu fused into GEMM2 load)
  gemm_kernel<64, true><<<(N + 63) / 64, 256, 0, stream>>>(out1, W2, g, N);
  agg_kernel<64><<<2048, 256, 0, stream>>>(row_start, csr_src, dis, g, b2, out, N);
}

// Round 3
// 607.090 us; speedup vs baseline: 2.4552x; 1.3663x over previous
//
#include <hip/hip_runtime.h>

// GCN 2-layer inference via CSR gather + register-blocked fp32 GEMM.
static constexpr int NPAD = 131072;

__global__ __launch_bounds__(256) void deg_kernel(const int* __restrict__ dst,
                                                  int* __restrict__ degi, int nE) {
  int i = blockIdx.x * 256 + threadIdx.x;
  if (i < nE) atomicAdd(&degi[dst[i]], 1);
}

__global__ __launch_bounds__(256) void dis_kernel(const int* __restrict__ degi,
                                                  float* __restrict__ dis, int n) {
  int i = blockIdx.x * 256 + threadIdx.x;
  if (i < n) dis[i] = rsqrtf((float)degi[i] + 1.0f);  // +1 = self loop
}

__global__ __launch_bounds__(256) void block_sum_kernel(const int* __restrict__ degi,
                                                        int* __restrict__ bsum, int n) {
  __shared__ int sm[256];
  int i = blockIdx.x * 256 + threadIdx.x;
  sm[threadIdx.x] = (i < n) ? degi[i] : 0;
  __syncthreads();
  for (int s = 128; s > 0; s >>= 1) {
    if (threadIdx.x < s) sm[threadIdx.x] += sm[threadIdx.x + s];
    __syncthreads();
  }
  if (threadIdx.x == 0) bsum[blockIdx.x] = sm[0];
}

__global__ __launch_bounds__(512) void scan_bsum_kernel(int* __restrict__ bsum, int nb) {
  __shared__ int sm[512];
  int v = (threadIdx.x < nb) ? bsum[threadIdx.x] : 0;
  sm[threadIdx.x] = v;
  __syncthreads();
  for (int off = 1; off < 512; off <<= 1) {
    int t = (threadIdx.x >= off) ? sm[threadIdx.x - off] : 0;
    __syncthreads();
    sm[threadIdx.x] += t;
    __syncthreads();
  }
  if (threadIdx.x < nb) bsum[threadIdx.x] = sm[threadIdx.x] - v;  // exclusive
}

__global__ __launch_bounds__(256) void scan_local_kernel(const int* __restrict__ degi,
                                                         const int* __restrict__ bsum,
                                                         int* __restrict__ row_start,
                                                         int* __restrict__ cursor, int n) {
  __shared__ int sm[256];
  int i = blockIdx.x * 256 + threadIdx.x;
  int v = (i < n) ? degi[i] : 0;
  sm[threadIdx.x] = v;
  __syncthreads();
  for (int off = 1; off < 256; off <<= 1) {
    int t = (threadIdx.x >= off) ? sm[threadIdx.x - off] : 0;
    __syncthreads();
    sm[threadIdx.x] += t;
    __syncthreads();
  }
  int excl = sm[threadIdx.x] - v + bsum[blockIdx.x];
  if (i < n) { row_start[i] = excl; cursor[i] = excl; }
  if (i == n - 1) row_start[n] = excl + v;  // = E
}

__global__ __launch_bounds__(256) void fill_csr_kernel(const int* __restrict__ src,
                                                       const int* __restrict__ dst,
                                                       int* __restrict__ cursor,
                                                       int* __restrict__ csr, int nE) {
  int i = blockIdx.x * 256 + threadIdx.x;
  if (i < nE) {
    int pos = atomicAdd(&cursor[dst[i]], 1);
    csr[pos] = src[i];
  }
}

// H[128rows x COLS] per block = X[128rows x 128] @ W[128 x COLS], K chunked by 32.
// Thread = 8 rows x TN cols register tile. TN=8 (COLS=128, cols split c/c+64) or 4.
template <int COLS, bool RELU_IN>
__global__ __launch_bounds__(256) void gemm_kernel(const float* __restrict__ X,
                                                   const float* __restrict__ W,
                                                   float* __restrict__ H, int n) {
  constexpr int KC = 32;
  constexpr int RT = 132;  // 128 rows + 4 pad (keeps float4 align, spreads banks)
  constexpr int TN = (COLS == 128) ? 8 : 4;
  __shared__ float sX[KC][RT];    // transposed: [k][row]
  __shared__ float sW[KC][COLS];  // [k][col]
  const int t = threadIdx.x;
  const int row0 = blockIdx.x * 128;
  const int r0 = (t >> 4) * 8;   // row group 0..15 -> 8 rows
  const int c0 = (t & 15) * 4;   // col group 0..15 -> 4 (+64) cols

  float acc[8][TN];
#pragma unroll
  for (int i = 0; i < 8; ++i)
#pragma unroll
    for (int j = 0; j < TN; ++j) acc[i][j] = 0.f;

  for (int k0 = 0; k0 < 128; k0 += KC) {
    // stage X tile (transposed into sX[k][row])
#pragma unroll
    for (int p = 0; p < 4; ++p) {
      int idx = p * 256 + t;
      int r = idx >> 3;       // 0..127
      int f = idx & 7;        // which float4 of the 32-k slice
      int gr = row0 + r;
      float4 v = make_float4(0.f, 0.f, 0.f, 0.f);
      if (gr < n) v = *(const float4*)(X + (size_t)gr * 128 + k0 + f * 4);
      if (RELU_IN) {
        v.x = fmaxf(v.x, 0.f); v.y = fmaxf(v.y, 0.f);
        v.z = fmaxf(v.z, 0.f); v.w = fmaxf(v.w, 0.f);
      }
      int kk = f * 4;
      sX[kk + 0][r] = v.x; sX[kk + 1][r] = v.y;
      sX[kk + 2][r] = v.z; sX[kk + 3][r] = v.w;
    }
    // stage W tile
    constexpr int WP = (KC * COLS) / (256 * 4);
#pragma unroll
    for (int p = 0; p < WP; ++p) {
      int idx = p * 256 + t;            // float4 index
      int k = idx / (COLS / 4);
      int c4 = idx % (COLS / 4);
      *(float4*)&sW[k][c4 * 4] = *(const float4*)(W + (size_t)(k0 + k) * COLS + c4 * 4);
    }
    __syncthreads();
#pragma unroll 8
    for (int k = 0; k < KC; ++k) {
      float4 xa = *(const float4*)&sX[k][r0];
      float4 xb = *(const float4*)&sX[k][r0 + 4];
      float4 wa = *(const float4*)&sW[k][c0];
      float xr[8] = {xa.x, xa.y, xa.z, xa.w, xb.x, xb.y, xb.z, xb.w};
      if (COLS == 128) {
        float4 wb = *(const float4*)&sW[k][c0 + 64];
        float wr[8] = {wa.x, wa.y, wa.z, wa.w, wb.x, wb.y, wb.z, wb.w};
#pragma unroll
        for (int i = 0; i < 8; ++i)
#pragma unroll
          for (int j = 0; j < 8; ++j) acc[i][j] = fmaf(xr[i], wr[j], acc[i][j]);
      } else {
        float wr[4] = {wa.x, wa.y, wa.z, wa.w};
#pragma unroll
        for (int i = 0; i < 8; ++i)
#pragma unroll
          for (int j = 0; j < 4; ++j) acc[i][j] = fmaf(xr[i], wr[j], acc[i][j]);
      }
    }
    __syncthreads();
  }
  // epilogue
#pragma unroll
  for (int i = 0; i < 8; ++i) {
    int row = row0 + r0 + i;
    if (row >= n) break;
    float* hrow = H + (size_t)row * COLS;
    *(float4*)&hrow[c0] = make_float4(acc[i][0], acc[i][1], acc[i][2], acc[i][3]);
    if (COLS == 128)
      *(float4*)&hrow[c0 + 64] = make_float4(acc[i][4], acc[i][5], acc[i][6], acc[i][7]);
  }
}

// One wave per dst node: out[d] = dis[d]*(sum_{s in N(d)} dis[s]*h[s] + dis[d]*h[d]) + b
template <int COLS>
__global__ __launch_bounds__(256) void agg_kernel(const int* __restrict__ row_start,
                                                  const int* __restrict__ csr,
                                                  const float* __restrict__ dis,
                                                  const float* __restrict__ h,
                                                  const float* __restrict__ bias,
                                                  float* __restrict__ out, int n) {
  const int lane = threadIdx.x & 63;
  int wv = blockIdx.x * 4 + (threadIdx.x >> 6);
  const int nwv = gridDim.x * 4;
  for (int d = wv; d < n; d += nwv) {
    const int e0 = row_start[d], e1 = row_start[d + 1];
    const float dd = dis[d];
    if (COLS == 128) {
      float2 hv = ((const float2*)(h + (size_t)d * 128))[lane];
      float acx = dd * hv.x, acy = dd * hv.y;
      int e = e0;
      for (; e + 1 < e1; e += 2) {
        int sa = csr[e], sb = csr[e + 1];
        float wa = dis[sa], wb = dis[sb];
        float2 ha = ((const float2*)(h + (size_t)sa * 128))[lane];
        float2 hb = ((const float2*)(h + (size_t)sb * 128))[lane];
        acx = fmaf(wa, ha.x, acx); acy = fmaf(wa, ha.y, acy);
        acx = fmaf(wb, hb.x, acx); acy = fmaf(wb, hb.y, acy);
      }
      if (e < e1) {
        int sa = csr[e];
        float wa = dis[sa];
        float2 ha = ((const float2*)(h + (size_t)sa * 128))[lane];
        acx = fmaf(wa, ha.x, acx); acy = fmaf(wa, ha.y, acy);
      }
      float2 bv = ((const float2*)bias)[lane];
      float2 o;
      o.x = fmaf(dd, acx, bv.x);
      o.y = fmaf(dd, acy, bv.y);
      ((float2*)(out + (size_t)d * 128))[lane] = o;
    } else {
      float acc = dd * h[(size_t)d * 64 + lane];
      int e = e0;
      for (; e + 1 < e1; e += 2) {
        int sa = csr[e], sb = csr[e + 1];
        float wa = dis[sa], wb = dis[sb];
        float ha = h[(size_t)sa * 64 + lane];
        float hb = h[(size_t)sb * 64 + lane];
        acc = fmaf(wa, ha, acc);
        acc = fmaf(wb, hb, acc);
      }
      if (e < e1) {
        int sa = csr[e];
        acc = fmaf(dis[sa], h[(size_t)sa * 64 + lane], acc);
      }
      out[(size_t)d * 64 + lane] = fmaf(dd, acc, bias[lane]);
    }
  }
}

extern "C" void kernel_launch(void* const* d_in, const int* in_sizes, int n_in,
                              void* d_out, int out_size, void* d_ws, size_t ws_size,
                              hipStream_t stream) {
  const float* x  = (const float*)d_in[0];
  const int* ei   = (const int*)d_in[1];   // [2, E] int32
  const float* W1 = (const float*)d_in[2];
  const float* b1 = (const float*)d_in[3];
  const float* W2 = (const float*)d_in[4];
  const float* b2 = (const float*)d_in[5];
  float* out = (float*)d_out;

  const int N = in_sizes[0] / 128;  // 100000
  const int E = in_sizes[1] / 2;    // 1600000
  const int* srcI = ei;
  const int* dstI = ei + E;

  char* w = (char*)d_ws;
  float* dis      = (float*)w;                 w += (size_t)NPAD * 4;
  int* degi       = (int*)w;                   w += (size_t)NPAD * 4;
  int* row_start  = (int*)w;                   w += (size_t)NPAD * 4;
  int* cursor     = (int*)w;                   w += (size_t)NPAD * 4;
  int* bsum       = (int*)w;                   w += 4096 * 4;
  int* csr_src    = (int*)w;                   w += (size_t)E * 4;
  float* h        = (float*)w;                 w += (size_t)N * 128 * 4;
  float* out1     = (float*)w;
  float* g        = h;  // layer-2 GEMM out aliases dead h

  const int nb = (N + 255) / 256;  // 391 <= 512

  // CSR build
  hipMemsetAsync(degi, 0, (size_t)N * sizeof(int), stream);
  deg_kernel<<<(E + 255) / 256, 256, 0, stream>>>(dstI, degi, E);
  dis_kernel<<<(N + 255) / 256, 256, 0, stream>>>(degi, dis, N);
  block_sum_kernel<<<nb, 256, 0, stream>>>(degi, bsum, N);
  scan_bsum_kernel<<<1, 512, 0, stream>>>(bsum, nb);
  scan_local_kernel<<<nb, 256, 0, stream>>>(degi, bsum, row_start, cursor, N);
  fill_csr_kernel<<<(E + 255) / 256, 256, 0, stream>>>(srcI, dstI, cursor, csr_src, E);

  // layer 1
  gemm_kernel<128, false><<<(N + 127) / 128, 256, 0, stream>>>(x, W1, h, N);
  agg_kernel<128><<<2048, 256, 0, stream>>>(row_start, csr_src, dis, h, b1, out1, N);

  // layer 2 (relu fused into GEMM2 load)
  gemm_kernel<64, true><<<(N + 127) / 128, 256, 0, stream>>>(out1, W2, g, N);
  agg_kernel<64><<<2048, 256, 0, stream>>>(row_start, csr_src, dis, g, b2, out, N);
}

// Round 4
// 472.792 us; speedup vs baseline: 3.1526x; 1.2841x over previous
//
#include <hip/hip_runtime.h>

// GCN 2-layer inference: CSR gather w/ bf16 payload + precomputed edge weights.
static constexpr int NPAD = 131072;
typedef unsigned int uint32;

__device__ __forceinline__ ushort f2bf(float f) {  // RNE f32->bf16
  uint32 u = __float_as_uint(f);
  return (ushort)((u + 0x7FFF + ((u >> 16) & 1)) >> 16);
}
__device__ __forceinline__ float bf_lo(uint32 u) { return __uint_as_float(u << 16); }
__device__ __forceinline__ float bf_hi(uint32 u) { return __uint_as_float(u & 0xFFFF0000u); }

__global__ __launch_bounds__(256) void deg_kernel(const int* __restrict__ dst,
                                                  int* __restrict__ degi, int nE) {
  int i = blockIdx.x * 256 + threadIdx.x;
  if (i < nE) atomicAdd(&degi[dst[i]], 1);
}

__global__ __launch_bounds__(256) void dis_kernel(const int* __restrict__ degi,
                                                  float* __restrict__ dis, int n) {
  int i = blockIdx.x * 256 + threadIdx.x;
  if (i < n) dis[i] = rsqrtf((float)degi[i] + 1.0f);  // +1 = self loop
}

__global__ __launch_bounds__(256) void block_sum_kernel(const int* __restrict__ degi,
                                                        int* __restrict__ bsum, int n) {
  __shared__ int sm[256];
  int i = blockIdx.x * 256 + threadIdx.x;
  sm[threadIdx.x] = (i < n) ? degi[i] : 0;
  __syncthreads();
  for (int s = 128; s > 0; s >>= 1) {
    if (threadIdx.x < s) sm[threadIdx.x] += sm[threadIdx.x + s];
    __syncthreads();
  }
  if (threadIdx.x == 0) bsum[blockIdx.x] = sm[0];
}

__global__ __launch_bounds__(512) void scan_bsum_kernel(int* __restrict__ bsum, int nb) {
  __shared__ int sm[512];
  int v = (threadIdx.x < nb) ? bsum[threadIdx.x] : 0;
  sm[threadIdx.x] = v;
  __syncthreads();
  for (int off = 1; off < 512; off <<= 1) {
    int t = (threadIdx.x >= off) ? sm[threadIdx.x - off] : 0;
    __syncthreads();
    sm[threadIdx.x] += t;
    __syncthreads();
  }
  if (threadIdx.x < nb) bsum[threadIdx.x] = sm[threadIdx.x] - v;  // exclusive
}

__global__ __launch_bounds__(256) void scan_local_kernel(const int* __restrict__ degi,
                                                         const int* __restrict__ bsum,
                                                         int* __restrict__ row_start,
                                                         int* __restrict__ cursor, int n) {
  __shared__ int sm[256];
  int i = blockIdx.x * 256 + threadIdx.x;
  int v = (i < n) ? degi[i] : 0;
  sm[threadIdx.x] = v;
  __syncthreads();
  for (int off = 1; off < 256; off <<= 1) {
    int t = (threadIdx.x >= off) ? sm[threadIdx.x - off] : 0;
    __syncthreads();
    sm[threadIdx.x] += t;
    __syncthreads();
  }
  int excl = sm[threadIdx.x] - v + bsum[blockIdx.x];
  if (i < n) { row_start[i] = excl; cursor[i] = excl; }
  if (i == n - 1) row_start[n] = excl + v;  // = E
}

__global__ __launch_bounds__(256) void fill_csr_kernel(const int* __restrict__ src,
                                                       const int* __restrict__ dst,
                                                       const float* __restrict__ dis,
                                                       int* __restrict__ cursor,
                                                       int* __restrict__ csr,
                                                       float* __restrict__ csr_w, int nE) {
  int i = blockIdx.x * 256 + threadIdx.x;
  if (i < nE) {
    int s = src[i], d = dst[i];
    int pos = atomicAdd(&cursor[d], 1);
    csr[pos] = s;
    csr_w[pos] = dis[s] * dis[d];
  }
}

// H_bf16[128rows x COLS] per block = (relu?)X[128rows x 128] @ W[128 x COLS].
template <int COLS, bool RELU_IN>
__global__ __launch_bounds__(256) void gemm_kernel(const float* __restrict__ X,
                                                   const float* __restrict__ W,
                                                   ushort* __restrict__ H, int n) {
  constexpr int KC = 32;
  constexpr int RT = 132;
  constexpr int TN = (COLS == 128) ? 8 : 4;
  __shared__ float sX[KC][RT];
  __shared__ float sW[KC][COLS];
  const int t = threadIdx.x;
  const int row0 = blockIdx.x * 128;
  const int r0 = (t >> 4) * 8;
  const int c0 = (t & 15) * 4;

  float acc[8][TN];
#pragma unroll
  for (int i = 0; i < 8; ++i)
#pragma unroll
    for (int j = 0; j < TN; ++j) acc[i][j] = 0.f;

  for (int k0 = 0; k0 < 128; k0 += KC) {
#pragma unroll
    for (int p = 0; p < 4; ++p) {
      int idx = p * 256 + t;
      int r = idx >> 3;
      int f = idx & 7;
      int gr = row0 + r;
      float4 v = make_float4(0.f, 0.f, 0.f, 0.f);
      if (gr < n) v = *(const float4*)(X + (size_t)gr * 128 + k0 + f * 4);
      if (RELU_IN) {
        v.x = fmaxf(v.x, 0.f); v.y = fmaxf(v.y, 0.f);
        v.z = fmaxf(v.z, 0.f); v.w = fmaxf(v.w, 0.f);
      }
      int kk = f * 4;
      sX[kk + 0][r] = v.x; sX[kk + 1][r] = v.y;
      sX[kk + 2][r] = v.z; sX[kk + 3][r] = v.w;
    }
    constexpr int WP = (KC * COLS) / (256 * 4);
#pragma unroll
    for (int p = 0; p < WP; ++p) {
      int idx = p * 256 + t;
      int k = idx / (COLS / 4);
      int c4 = idx % (COLS / 4);
      *(float4*)&sW[k][c4 * 4] = *(const float4*)(W + (size_t)(k0 + k) * COLS + c4 * 4);
    }
    __syncthreads();
#pragma unroll 8
    for (int k = 0; k < KC; ++k) {
      float4 xa = *(const float4*)&sX[k][r0];
      float4 xb = *(const float4*)&sX[k][r0 + 4];
      float4 wa = *(const float4*)&sW[k][c0];
      float xr[8] = {xa.x, xa.y, xa.z, xa.w, xb.x, xb.y, xb.z, xb.w};
      if (COLS == 128) {
        float4 wb = *(const float4*)&sW[k][c0 + 64];
        float wr[8] = {wa.x, wa.y, wa.z, wa.w, wb.x, wb.y, wb.z, wb.w};
#pragma unroll
        for (int i = 0; i < 8; ++i)
#pragma unroll
          for (int j = 0; j < 8; ++j) acc[i][j] = fmaf(xr[i], wr[j], acc[i][j]);
      } else {
        float wr[4] = {wa.x, wa.y, wa.z, wa.w};
#pragma unroll
        for (int i = 0; i < 8; ++i)
#pragma unroll
          for (int j = 0; j < 4; ++j) acc[i][j] = fmaf(xr[i], wr[j], acc[i][j]);
      }
    }
    __syncthreads();
  }
#pragma unroll
  for (int i = 0; i < 8; ++i) {
    int row = row0 + r0 + i;
    if (row >= n) break;
    ushort* hrow = H + (size_t)row * COLS;
    ushort4 s0;
    s0.x = f2bf(acc[i][0]); s0.y = f2bf(acc[i][1]);
    s0.z = f2bf(acc[i][2]); s0.w = f2bf(acc[i][3]);
    *(ushort4*)&hrow[c0] = s0;
    if (COLS == 128) {
      ushort4 s1;
      s1.x = f2bf(acc[i][4]); s1.y = f2bf(acc[i][5]);
      s1.z = f2bf(acc[i][6]); s1.w = f2bf(acc[i][7]);
      *(ushort4*)&hrow[c0 + 64] = s1;
    }
  }
}

// One wave per dst node: out[d] = sum_e w_e*h[s_e] + dis[d]^2*h[d] + b  (h in bf16)
template <int COLS>
__global__ __launch_bounds__(256) void agg_kernel(const int* __restrict__ row_start,
                                                  const int* __restrict__ csr,
                                                  const float* __restrict__ csr_w,
                                                  const float* __restrict__ dis,
                                                  const ushort* __restrict__ h,
                                                  const float* __restrict__ bias,
                                                  float* __restrict__ out, int n) {
  const int lane = threadIdx.x & 63;
  int wv = blockIdx.x * 4 + (threadIdx.x >> 6);
  const int nwv = gridDim.x * 4;
  for (int d = wv; d < n; d += nwv) {
    const int e0 = row_start[d], e1 = row_start[d + 1];
    const float dd = dis[d];
    if (COLS == 128) {
      uint32 hv = ((const uint32*)(h + (size_t)d * 128))[lane];
      float sq = dd * dd;
      float acx = sq * bf_lo(hv), acy = sq * bf_hi(hv);
      int e = e0;
      for (; e + 3 < e1; e += 4) {
        int s0 = csr[e], s1 = csr[e + 1], s2 = csr[e + 2], s3 = csr[e + 3];
        float w0 = csr_w[e], w1 = csr_w[e + 1], w2 = csr_w[e + 2], w3 = csr_w[e + 3];
        uint32 a0 = ((const uint32*)(h + (size_t)s0 * 128))[lane];
        uint32 a1 = ((const uint32*)(h + (size_t)s1 * 128))[lane];
        uint32 a2 = ((const uint32*)(h + (size_t)s2 * 128))[lane];
        uint32 a3 = ((const uint32*)(h + (size_t)s3 * 128))[lane];
        acx = fmaf(w0, bf_lo(a0), acx); acy = fmaf(w0, bf_hi(a0), acy);
        acx = fmaf(w1, bf_lo(a1), acx); acy = fmaf(w1, bf_hi(a1), acy);
        acx = fmaf(w2, bf_lo(a2), acx); acy = fmaf(w2, bf_hi(a2), acy);
        acx = fmaf(w3, bf_lo(a3), acx); acy = fmaf(w3, bf_hi(a3), acy);
      }
      for (; e < e1; ++e) {
        int s0 = csr[e];
        float w0 = csr_w[e];
        uint32 a0 = ((const uint32*)(h + (size_t)s0 * 128))[lane];
        acx = fmaf(w0, bf_lo(a0), acx); acy = fmaf(w0, bf_hi(a0), acy);
      }
      float2 bv = ((const float2*)bias)[lane];
      ((float2*)(out + (size_t)d * 128))[lane] = make_float2(acx + bv.x, acy + bv.y);
    } else {
      float acc = dd * dd * bf_lo((uint32)h[(size_t)d * 64 + lane]);
      int e = e0;
      for (; e + 3 < e1; e += 4) {
        int s0 = csr[e], s1 = csr[e + 1], s2 = csr[e + 2], s3 = csr[e + 3];
        float w0 = csr_w[e], w1 = csr_w[e + 1], w2 = csr_w[e + 2], w3 = csr_w[e + 3];
        float a0 = bf_lo((uint32)h[(size_t)s0 * 64 + lane]);
        float a1 = bf_lo((uint32)h[(size_t)s1 * 64 + lane]);
        float a2 = bf_lo((uint32)h[(size_t)s2 * 64 + lane]);
        float a3 = bf_lo((uint32)h[(size_t)s3 * 64 + lane]);
        acc = fmaf(w0, a0, acc); acc = fmaf(w1, a1, acc);
        acc = fmaf(w2, a2, acc); acc = fmaf(w3, a3, acc);
      }
      for (; e < e1; ++e)
        acc = fmaf(csr_w[e], bf_lo((uint32)h[(size_t)csr[e] * 64 + lane]), acc);
      out[(size_t)d * 64 + lane] = acc + bias[lane];
    }
  }
}

extern "C" void kernel_launch(void* const* d_in, const int* in_sizes, int n_in,
                              void* d_out, int out_size, void* d_ws, size_t ws_size,
                              hipStream_t stream) {
  const float* x  = (const float*)d_in[0];
  const int* ei   = (const int*)d_in[1];   // [2, E] int32
  const float* W1 = (const float*)d_in[2];
  const float* b1 = (const float*)d_in[3];
  const float* W2 = (const float*)d_in[4];
  const float* b2 = (const float*)d_in[5];
  float* out = (float*)d_out;

  const int N = in_sizes[0] / 128;  // 100000
  const int E = in_sizes[1] / 2;    // 1600000
  const int* srcI = ei;
  const int* dstI = ei + E;

  char* w = (char*)d_ws;
  float* dis      = (float*)w;                 w += (size_t)NPAD * 4;
  int* degi       = (int*)w;                   w += (size_t)NPAD * 4;
  int* row_start  = (int*)w;                   w += (size_t)NPAD * 4;
  int* cursor     = (int*)w;                   w += (size_t)NPAD * 4;
  int* bsum       = (int*)w;                   w += 4096 * 4;
  int* csr_src    = (int*)w;                   w += (size_t)E * 4;
  float* csr_w    = (float*)w;                 w += (size_t)E * 4;
  ushort* h       = (ushort*)w;                w += (size_t)N * 128 * 2;  // bf16
  float* out1     = (float*)w;
  ushort* g       = h;  // layer-2 bf16 out aliases dead h

  const int nb = (N + 255) / 256;  // 391 <= 512

  // CSR build
  hipMemsetAsync(degi, 0, (size_t)N * sizeof(int), stream);
  deg_kernel<<<(E + 255) / 256, 256, 0, stream>>>(dstI, degi, E);
  dis_kernel<<<(N + 255) / 256, 256, 0, stream>>>(degi, dis, N);
  block_sum_kernel<<<nb, 256, 0, stream>>>(degi, bsum, N);
  scan_bsum_kernel<<<1, 512, 0, stream>>>(bsum, nb);
  scan_local_kernel<<<nb, 256, 0, stream>>>(degi, bsum, row_start, cursor, N);
  fill_csr_kernel<<<(E + 255) / 256, 256, 0, stream>>>(srcI, dstI, dis, cursor, csr_src, csr_w, E);

  // layer 1
  gemm_kernel<128, false><<<(N + 127) / 128, 256, 0, stream>>>(x, W1, h, N);
  agg_kernel<128><<<2048, 256, 0, stream>>>(row_start, csr_src, csr_w, dis, h, b1, out1, N);

  // layer 2 (relu fused into GEMM2 load)
  gemm_kernel<64, true><<<(N + 127) / 128, 256, 0, stream>>>(out1, W2, g, N);
  agg_kernel<64><<<2048, 256, 0, stream>>>(row_start, csr_src, csr_w, dis, g, b2, out, N);
}

// Round 5
// 469.987 us; speedup vs baseline: 3.1714x; 1.0060x over previous
//
#include <hip/hip_runtime.h>

// GCN 2-layer inference: CSR gather w/ bf16 payload, packed (src,w) CSR entries,
// XCD-partitioned CSR build (scatter stays L2-local per XCD).
static constexpr int NPAD = 131072;
typedef unsigned int uint32;

__device__ __forceinline__ ushort f2bf(float f) {  // RNE f32->bf16
  uint32 u = __float_as_uint(f);
  return (ushort)((u + 0x7FFF + ((u >> 16) & 1)) >> 16);
}
__device__ __forceinline__ float bf_lo(uint32 u) { return __uint_as_float(u << 16); }
__device__ __forceinline__ float bf_hi(uint32 u) { return __uint_as_float(u & 0xFFFF0000u); }

// XCD-partitioned degree histogram: xcd-group g only counts dst in its slice,
// so atomics stay in the local L2.
__global__ __launch_bounds__(256) void deg_kernel(const int* __restrict__ dst,
                                                  int* __restrict__ degi, int nE,
                                                  int nPerXcd) {
  const int xcd = blockIdx.x & 7;
  const int sub = blockIdx.x >> 3;
  const int nsub = gridDim.x >> 3;
  const int lo = xcd * nPerXcd, hi = lo + nPerXcd;
  for (int i = sub * 256 + threadIdx.x; i < nE; i += nsub * 256) {
    int d = dst[i];
    if (d >= lo && d < hi) atomicAdd(&degi[d], 1);
  }
}

__global__ __launch_bounds__(256) void dis_kernel(const int* __restrict__ degi,
                                                  float* __restrict__ dis, int n) {
  int i = blockIdx.x * 256 + threadIdx.x;
  if (i < n) dis[i] = rsqrtf((float)degi[i] + 1.0f);  // +1 = self loop
}

__global__ __launch_bounds__(256) void block_sum_kernel(const int* __restrict__ degi,
                                                        int* __restrict__ bsum, int n) {
  __shared__ int sm[256];
  int i = blockIdx.x * 256 + threadIdx.x;
  sm[threadIdx.x] = (i < n) ? degi[i] : 0;
  __syncthreads();
  for (int s = 128; s > 0; s >>= 1) {
    if (threadIdx.x < s) sm[threadIdx.x] += sm[threadIdx.x + s];
    __syncthreads();
  }
  if (threadIdx.x == 0) bsum[blockIdx.x] = sm[0];
}

__global__ __launch_bounds__(512) void scan_bsum_kernel(int* __restrict__ bsum, int nb) {
  __shared__ int sm[512];
  int v = (threadIdx.x < nb) ? bsum[threadIdx.x] : 0;
  sm[threadIdx.x] = v;
  __syncthreads();
  for (int off = 1; off < 512; off <<= 1) {
    int t = (threadIdx.x >= off) ? sm[threadIdx.x - off] : 0;
    __syncthreads();
    sm[threadIdx.x] += t;
    __syncthreads();
  }
  if (threadIdx.x < nb) bsum[threadIdx.x] = sm[threadIdx.x] - v;  // exclusive
}

__global__ __launch_bounds__(256) void scan_local_kernel(const int* __restrict__ degi,
                                                         const int* __restrict__ bsum,
                                                         int* __restrict__ row_start,
                                                         int* __restrict__ cursor, int n) {
  __shared__ int sm[256];
  int i = blockIdx.x * 256 + threadIdx.x;
  int v = (i < n) ? degi[i] : 0;
  sm[threadIdx.x] = v;
  __syncthreads();
  for (int off = 1; off < 256; off <<= 1) {
    int t = (threadIdx.x >= off) ? sm[threadIdx.x - off] : 0;
    __syncthreads();
    sm[threadIdx.x] += t;
    __syncthreads();
  }
  int excl = sm[threadIdx.x] - v + bsum[blockIdx.x];
  if (i < n) { row_start[i] = excl; cursor[i] = excl; }
  if (i == n - 1) row_start[n] = excl + v;  // = E
}

// XCD-partitioned CSR fill: one packed 8B (src, weight) store per edge, into a
// per-XCD 1.6MB slice that fits the local L2 -> no write amplification.
__global__ __launch_bounds__(256) void fill_csr_kernel(const int* __restrict__ src,
                                                       const int* __restrict__ dst,
                                                       const float* __restrict__ dis,
                                                       int* __restrict__ cursor,
                                                       uint2* __restrict__ csr_pack,
                                                       int nE, int nPerXcd) {
  const int xcd = blockIdx.x & 7;
  const int sub = blockIdx.x >> 3;
  const int nsub = gridDim.x >> 3;
  const int lo = xcd * nPerXcd, hi = lo + nPerXcd;
  for (int i = sub * 256 + threadIdx.x; i < nE; i += nsub * 256) {
    int d = dst[i];
    if (d >= lo && d < hi) {
      int s = src[i];
      int pos = atomicAdd(&cursor[d], 1);
      csr_pack[pos] = make_uint2((uint32)s, __float_as_uint(dis[s] * dis[d]));
    }
  }
}

// H_bf16[128rows x COLS] per block = (relu?)X[128rows x 128] @ W[128 x COLS].
template <int COLS, bool RELU_IN>
__global__ __launch_bounds__(256) void gemm_kernel(const float* __restrict__ X,
                                                   const float* __restrict__ W,
                                                   ushort* __restrict__ H, int n) {
  constexpr int KC = 32;
  constexpr int RT = 132;
  constexpr int TN = (COLS == 128) ? 8 : 4;
  __shared__ float sX[KC][RT];
  __shared__ float sW[KC][COLS];
  const int t = threadIdx.x;
  const int row0 = blockIdx.x * 128;
  const int r0 = (t >> 4) * 8;
  const int c0 = (t & 15) * 4;

  float acc[8][TN];
#pragma unroll
  for (int i = 0; i < 8; ++i)
#pragma unroll
    for (int j = 0; j < TN; ++j) acc[i][j] = 0.f;

  for (int k0 = 0; k0 < 128; k0 += KC) {
#pragma unroll
    for (int p = 0; p < 4; ++p) {
      int idx = p * 256 + t;
      int r = idx >> 3;
      int f = idx & 7;
      int gr = row0 + r;
      float4 v = make_float4(0.f, 0.f, 0.f, 0.f);
      if (gr < n) v = *(const float4*)(X + (size_t)gr * 128 + k0 + f * 4);
      if (RELU_IN) {
        v.x = fmaxf(v.x, 0.f); v.y = fmaxf(v.y, 0.f);
        v.z = fmaxf(v.z, 0.f); v.w = fmaxf(v.w, 0.f);
      }
      int kk = f * 4;
      sX[kk + 0][r] = v.x; sX[kk + 1][r] = v.y;
      sX[kk + 2][r] = v.z; sX[kk + 3][r] = v.w;
    }
    constexpr int WP = (KC * COLS) / (256 * 4);
#pragma unroll
    for (int p = 0; p < WP; ++p) {
      int idx = p * 256 + t;
      int k = idx / (COLS / 4);
      int c4 = idx % (COLS / 4);
      *(float4*)&sW[k][c4 * 4] = *(const float4*)(W + (size_t)(k0 + k) * COLS + c4 * 4);
    }
    __syncthreads();
#pragma unroll 8
    for (int k = 0; k < KC; ++k) {
      float4 xa = *(const float4*)&sX[k][r0];
      float4 xb = *(const float4*)&sX[k][r0 + 4];
      float4 wa = *(const float4*)&sW[k][c0];
      float xr[8] = {xa.x, xa.y, xa.z, xa.w, xb.x, xb.y, xb.z, xb.w};
      if (COLS == 128) {
        float4 wb = *(const float4*)&sW[k][c0 + 64];
        float wr[8] = {wa.x, wa.y, wa.z, wa.w, wb.x, wb.y, wb.z, wb.w};
#pragma unroll
        for (int i = 0; i < 8; ++i)
#pragma unroll
          for (int j = 0; j < 8; ++j) acc[i][j] = fmaf(xr[i], wr[j], acc[i][j]);
      } else {
        float wr[4] = {wa.x, wa.y, wa.z, wa.w};
#pragma unroll
        for (int i = 0; i < 8; ++i)
#pragma unroll
          for (int j = 0; j < 4; ++j) acc[i][j] = fmaf(xr[i], wr[j], acc[i][j]);
      }
    }
    __syncthreads();
  }
#pragma unroll
  for (int i = 0; i < 8; ++i) {
    int row = row0 + r0 + i;
    if (row >= n) break;
    ushort* hrow = H + (size_t)row * COLS;
    ushort4 s0;
    s0.x = f2bf(acc[i][0]); s0.y = f2bf(acc[i][1]);
    s0.z = f2bf(acc[i][2]); s0.w = f2bf(acc[i][3]);
    *(ushort4*)&hrow[c0] = s0;
    if (COLS == 128) {
      ushort4 s1;
      s1.x = f2bf(acc[i][4]); s1.y = f2bf(acc[i][5]);
      s1.z = f2bf(acc[i][6]); s1.w = f2bf(acc[i][7]);
      *(ushort4*)&hrow[c0 + 64] = s1;
    }
  }
}

// One wave per dst node: out[d] = sum_e w_e*h[s_e] + dis[d]^2*h[d] + b  (h in bf16)
template <int COLS>
__global__ __launch_bounds__(256) void agg_kernel(const int* __restrict__ row_start,
                                                  const uint2* __restrict__ csr,
                                                  const float* __restrict__ dis,
                                                  const ushort* __restrict__ h,
                                                  const float* __restrict__ bias,
                                                  float* __restrict__ out, int n) {
  const int lane = threadIdx.x & 63;
  int wv = blockIdx.x * 4 + (threadIdx.x >> 6);
  const int nwv = gridDim.x * 4;
  for (int d = wv; d < n; d += nwv) {
    const int e0 = row_start[d], e1 = row_start[d + 1];
    const float dd = dis[d];
    if (COLS == 128) {
      uint32 hv = ((const uint32*)(h + (size_t)d * 128))[lane];
      float sq = dd * dd;
      float acx = sq * bf_lo(hv), acy = sq * bf_hi(hv);
      int e = e0;
      for (; e + 3 < e1; e += 4) {
        uint2 p0 = csr[e], p1 = csr[e + 1], p2 = csr[e + 2], p3 = csr[e + 3];
        uint32 a0 = ((const uint32*)(h + (size_t)p0.x * 128))[lane];
        uint32 a1 = ((const uint32*)(h + (size_t)p1.x * 128))[lane];
        uint32 a2 = ((const uint32*)(h + (size_t)p2.x * 128))[lane];
        uint32 a3 = ((const uint32*)(h + (size_t)p3.x * 128))[lane];
        float w0 = __uint_as_float(p0.y), w1 = __uint_as_float(p1.y);
        float w2 = __uint_as_float(p2.y), w3 = __uint_as_float(p3.y);
        acx = fmaf(w0, bf_lo(a0), acx); acy = fmaf(w0, bf_hi(a0), acy);
        acx = fmaf(w1, bf_lo(a1), acx); acy = fmaf(w1, bf_hi(a1), acy);
        acx = fmaf(w2, bf_lo(a2), acx); acy = fmaf(w2, bf_hi(a2), acy);
        acx = fmaf(w3, bf_lo(a3), acx); acy = fmaf(w3, bf_hi(a3), acy);
      }
      for (; e < e1; ++e) {
        uint2 p0 = csr[e];
        float w0 = __uint_as_float(p0.y);
        uint32 a0 = ((const uint32*)(h + (size_t)p0.x * 128))[lane];
        acx = fmaf(w0, bf_lo(a0), acx); acy = fmaf(w0, bf_hi(a0), acy);
      }
      float2 bv = ((const float2*)bias)[lane];
      ((float2*)(out + (size_t)d * 128))[lane] = make_float2(acx + bv.x, acy + bv.y);
    } else {
      float acc = dd * dd * bf_lo((uint32)h[(size_t)d * 64 + lane]);
      int e = e0;
      for (; e + 3 < e1; e += 4) {
        uint2 p0 = csr[e], p1 = csr[e + 1], p2 = csr[e + 2], p3 = csr[e + 3];
        float a0 = bf_lo((uint32)h[(size_t)p0.x * 64 + lane]);
        float a1 = bf_lo((uint32)h[(size_t)p1.x * 64 + lane]);
        float a2 = bf_lo((uint32)h[(size_t)p2.x * 64 + lane]);
        float a3 = bf_lo((uint32)h[(size_t)p3.x * 64 + lane]);
        acc = fmaf(__uint_as_float(p0.y), a0, acc);
        acc = fmaf(__uint_as_float(p1.y), a1, acc);
        acc = fmaf(__uint_as_float(p2.y), a2, acc);
        acc = fmaf(__uint_as_float(p3.y), a3, acc);
      }
      for (; e < e1; ++e) {
        uint2 p0 = csr[e];
        acc = fmaf(__uint_as_float(p0.y), bf_lo((uint32)h[(size_t)p0.x * 64 + lane]), acc);
      }
      out[(size_t)d * 64 + lane] = acc + bias[lane];
    }
  }
}

extern "C" void kernel_launch(void* const* d_in, const int* in_sizes, int n_in,
                              void* d_out, int out_size, void* d_ws, size_t ws_size,
                              hipStream_t stream) {
  const float* x  = (const float*)d_in[0];
  const int* ei   = (const int*)d_in[1];   // [2, E] int32
  const float* W1 = (const float*)d_in[2];
  const float* b1 = (const float*)d_in[3];
  const float* W2 = (const float*)d_in[4];
  const float* b2 = (const float*)d_in[5];
  float* out = (float*)d_out;

  const int N = in_sizes[0] / 128;  // 100000
  const int E = in_sizes[1] / 2;    // 1600000
  const int* srcI = ei;
  const int* dstI = ei + E;
  const int nPerXcd = (N + 7) / 8;

  char* w = (char*)d_ws;
  float* dis      = (float*)w;                 w += (size_t)NPAD * 4;
  int* degi       = (int*)w;                   w += (size_t)NPAD * 4;
  int* row_start  = (int*)w;                   w += (size_t)NPAD * 4;
  int* cursor     = (int*)w;                   w += (size_t)NPAD * 4;
  int* bsum       = (int*)w;                   w += 4096 * 4;
  uint2* csr_pack = (uint2*)w;                 w += (size_t)E * 8;
  ushort* h       = (ushort*)w;                w += (size_t)N * 128 * 2;  // bf16
  float* out1     = (float*)w;
  ushort* g       = h;  // layer-2 bf16 out aliases dead h

  const int nb = (N + 255) / 256;  // 391 <= 512

  // CSR build (deg + fill are XCD-partitioned by dst range)
  hipMemsetAsync(degi, 0, (size_t)N * sizeof(int), stream);
  deg_kernel<<<2048, 256, 0, stream>>>(dstI, degi, E, nPerXcd);
  dis_kernel<<<(N + 255) / 256, 256, 0, stream>>>(degi, dis, N);
  block_sum_kernel<<<nb, 256, 0, stream>>>(degi, bsum, N);
  scan_bsum_kernel<<<1, 512, 0, stream>>>(bsum, nb);
  scan_local_kernel<<<nb, 256, 0, stream>>>(degi, bsum, row_start, cursor, N);
  fill_csr_kernel<<<2048, 256, 0, stream>>>(srcI, dstI, dis, cursor, csr_pack, E, nPerXcd);

  // layer 1
  gemm_kernel<128, false><<<(N + 127) / 128, 256, 0, stream>>>(x, W1, h, N);
  agg_kernel<128><<<2048, 256, 0, stream>>>(row_start, csr_pack, dis, h, b1, out1, N);

  // layer 2 (relu fused into GEMM2 load)
  gemm_kernel<64, true><<<(N + 127) / 128, 256, 0, stream>>>(out1, W2, g, N);
  agg_kernel<64><<<2048, 256, 0, stream>>>(row_start, csr_pack, dis, g, b2, out, N);
}